// Round 18
// baseline (398.043 us; speedup 1.0000x reference)
//
#include <hip/hip_runtime.h>
#include <math.h>

#define HID 128
#define HEAD 8
#define DK 16
#define FEDGE 10
#define FNODE 36
#define ESCALE 0.08838834764831845f  // 1/sqrt(128)
#define CH 32

typedef float f32x4v __attribute__((ext_vector_type(4)));
typedef short bf16x8 __attribute__((ext_vector_type(8)));

struct PackArgs {
  const float* src[8];
  unsigned short* dst[8];
  int fin[8];
  int kt[8];
  int blk_off[8];
};

struct PrepArgs {
  const float* We[3];
  const float* Wq[3];
  const float* Wk[3];
  const float* Wv[3];
  float* C[3];
  float* WeWv[3];
  float* Gram[3];
  float* Wksum[3];
  int fin[3];
};

__device__ __forceinline__ void fma4(float4& z, float s, const float4& w) {
  z.x += s * w.x;
  z.y += s * w.y;
  z.z += s * w.z;
  z.w += s * w.w;
}

__device__ __forceinline__ unsigned short f2bf(float f) {
  unsigned int u = __float_as_uint(f);
  u += 0x7fffu + ((u >> 16) & 1u);
  return (unsigned short)(u >> 16);
}

__device__ __forceinline__ float bflo(unsigned int u) { return __uint_as_float(u << 16); }
__device__ __forceinline__ float bfhi(unsigned int u) { return __uint_as_float(u & 0xffff0000u); }

__device__ __forceinline__ void store_bf8(unsigned short* p, float4 a, float4 b) {
  uint4 u;
  u.x = (unsigned)f2bf(a.x) | ((unsigned)f2bf(a.y) << 16);
  u.y = (unsigned)f2bf(a.z) | ((unsigned)f2bf(a.w) << 16);
  u.z = (unsigned)f2bf(b.x) | ((unsigned)f2bf(b.y) << 16);
  u.w = (unsigned)f2bf(b.z) | ((unsigned)f2bf(b.w) << 16);
  *(uint4*)p = u;
}

// Fused setup: [0, wprepN) weight precompute; [wprepN, wprepN+wpackN) bf16 pack;
// rest: zero cnt. All parts independent (pack reads original weights).
__global__ __launch_bounds__(256) void k_setup(PrepArgs a, PackArgs pa, int wprepN, int wpackN,
                                               int* __restrict__ cnt, int nzero) {
  int b = blockIdx.x, d = threadIdx.x;
  __shared__ float sw[HID];
  if (b < wprepN) {
    int l = b / FEDGE, t = b - l * FEDGE;
    int fin = a.fin[l];
    const float* We = a.We[l];
    if (d < fin) sw[d] = We[t * fin + d];
    __syncthreads();
    if (d < 128) {
      const float* Wq = a.Wq[l];
      const float* Wv = a.Wv[l];
      const float* Wk = a.Wk[l];
      float c = 0.f, wv = 0.f;
      for (int i = 0; i < fin; ++i) {
        c += sw[i] * Wq[i * HID + d];
        wv += sw[i] * Wv[i * HID + d];
      }
      a.C[l][t * HID + d] = c;
      a.WeWv[l][t * HID + d] = wv;
      if (d < FEDGE) {
        float g = 0.f;
        for (int i = 0; i < fin; ++i) g += sw[i] * We[d * fin + i];
        a.Gram[l][t * FEDGE + d] = g;
      }
      for (int r = t; r < fin; r += FEDGE) {
        if (d < DK) {
          float s = 0.f;
#pragma unroll
          for (int hh = 0; hh < HEAD; ++hh) s += Wk[r * HID + hh * DK + d];
          a.Wksum[l][r * DK + d] = s;
        }
      }
    }
    return;
  }
  if (b < wprepN + wpackN) {
    if (d >= 64) return;
    int bb = b - wprepN;
    int lane = d;
    int m = 0;
#pragma unroll
    for (int i = 1; i < 8; ++i) m += (bb >= pa.blk_off[i]);
    int local = bb - pa.blk_off[m];
    int KT = pa.kt[m];
    int ct = local / KT, kt = local - ct * KT;
    const float* W = pa.src[m];
    int fin = pa.fin[m];
    int col = ct * 16 + (lane & 15);
    int kbase = kt * 32 + (lane >> 4) * 8;
    float v[8];
#pragma unroll
    for (int j = 0; j < 8; ++j) {
      int k = kbase + j;
      v[j] = (k < fin) ? W[k * HID + col] : 0.f;
    }
    store_bf8(pa.dst[m] + (size_t)local * 512 + lane * 8, make_float4(v[0], v[1], v[2], v[3]),
              make_float4(v[4], v[5], v[6], v[7]));
    return;
  }
  int i = (b - wprepN - wpackN) * 256 + d;
  if (i < nzero) cnt[i] = 0;
}

__global__ void k_count(const int* __restrict__ ei, int E, int* __restrict__ cnt) {
  int e = blockIdx.x * 256 + threadIdx.x;
  if (e >= E) return;
  atomicAdd(&cnt[ei[E + e]], 1);
}

__global__ __launch_bounds__(1024) void k_scan(const int* __restrict__ cnt, int* __restrict__ off,
                                               int* __restrict__ cur, int* __restrict__ scsr_s,
                                               int n, int total) {
  __shared__ int s[1024];
  int t = threadIdx.x;
  const int C = (n + 1023) / 1024;
  int local[32];
  int base = t * C;
  int sum = 0;
  for (int j = 0; j < C; ++j) {
    int i = base + j;
    int v = (i < n) ? cnt[i] : 0;
    local[j] = sum;
    sum += v;
  }
  s[t] = sum;
  __syncthreads();
  for (int dd = 1; dd < 1024; dd <<= 1) {
    int v = (t >= dd) ? s[t - dd] : 0;
    __syncthreads();
    s[t] += v;
    __syncthreads();
  }
  int excl = (t == 0) ? 0 : s[t - 1];
  for (int j = 0; j < C; ++j) {
    int i = base + j;
    if (i < n) {
      int o = excl + local[j];
      off[i] = o;
      cur[i] = o;
      scsr_s[o + i] = i;  // self-loop slot source = the node itself
    }
  }
  if (t == 0) off[n] = total;
}

// CSR fill + per-layer sea in one pass: node n's slots = [off[n]+n, off[n+1]+n+1),
// slot off[n]+n is the self-loop; edge e lands at pos = cur++ + t + 1.
__global__ void k_fill_sea(const int* __restrict__ ei, int E, int* __restrict__ cur,
                           int* __restrict__ scsr_s, const float* __restrict__ eattr,
                           const float* __restrict__ Gram3, float* __restrict__ sea3, int ET) {
  int e = blockIdx.x * 256 + threadIdx.x;
  if (e >= E) return;
  int t = ei[E + e];
  int pos = atomicAdd(&cur[t], 1) + t + 1;
  scsr_s[pos] = ei[e];
  float a[FEDGE];
  float ss = 0.f;
  for (int i = 0; i < FEDGE; ++i) {
    a[i] = eattr[(size_t)e * FEDGE + i];
    ss += a[i] * a[i];
  }
  float s0 = 1.f / fmaxf(sqrtf(ss), 1e-12f);
  for (int i = 0; i < FEDGE; ++i) a[i] *= s0;
  for (int l = 0; l < 3; ++l) {
    const float* G = Gram3 + l * FEDGE * FEDGE;
    float gp = 0.f;
#pragma unroll
    for (int j = 0; j < FEDGE; ++j) {
      float tt = 0.f;
#pragma unroll
      for (int u = 0; u < FEDGE; ++u) tt += G[j * FEDGE + u] * a[u];
      gp += tt * a[j];
    }
    float scl = 1.f / fmaxf(sqrtf(gp), 1e-12f);
    float* sp = sea3 + (size_t)l * ET * FEDGE + (size_t)pos * FEDGE;
#pragma unroll
    for (int u = 0; u < FEDGE; ++u) sp[u] = scl * a[u];
  }
}

// Layer-0 k1: l2norm(x) -> MFMA q/v (bf16, K padded 36->64), k/M fp32.
__global__ __launch_bounds__(256) void k1_l2x(
    const float* __restrict__ x, const unsigned short* __restrict__ qpack,
    const unsigned short* __restrict__ vpack, const float* __restrict__ Wksum,
    const float* __restrict__ C, unsigned short* __restrict__ qxh, float* __restrict__ kb,
    unsigned short* __restrict__ vxh, float* __restrict__ Mout, int N) {
  const int fin = FNODE;
  int d = threadIdx.x;
  int n0 = blockIdx.x * 16;
  int nb = min(16, N - n0);
  __shared__ __align__(16) float sx[16][40];
  __shared__ __align__(16) unsigned short afrag[2][64][8];
  __shared__ float sk[16][DK];
  {
    int col = d & 127, h2 = d >> 7;
#pragma unroll
    for (int rr = 0; rr < 8; ++rr) {
      int r = h2 * 8 + rr;
      if (col < fin) sx[r][col] = (r < nb) ? x[(size_t)(n0 + r) * fin + col] : 0.f;
    }
  }
  __syncthreads();
  int grp = d >> 4, j16 = d & 15;
  {  // l2norm row grp in-place
    float ssq = 0.f;
    for (int i = j16; i < fin; i += 16) ssq += sx[grp][i] * sx[grp][i];
#pragma unroll
    for (int o = 8; o; o >>= 1) ssq += __shfl_xor(ssq, o, 16);
    float scl = 1.f / fmaxf(sqrtf(ssq), 1e-12f);
    for (int i = j16; i < fin; i += 16) sx[grp][i] *= scl;
  }
  __syncthreads();
  int lane = d & 63, wvid = d >> 6;
  if (d < 128) {  // A-fragments (2 K-chunks of 32, zero-padded past fin)
    int kt = d >> 6;  // 0..1
    int m = lane & 15, k0 = kt * 32 + (lane >> 4) * 8;
    float v[8];
#pragma unroll
    for (int j = 0; j < 8; ++j) {
      int k = k0 + j;
      v[j] = (k < fin) ? sx[m][k] : 0.f;
    }
    store_bf8(&afrag[kt][lane][0], make_float4(v[0], v[1], v[2], v[3]),
              make_float4(v[4], v[5], v[6], v[7]));
  }
  {  // k = h @ Wksum (fp32)
    float kk = 0.f;
    for (int i = 0; i < fin; ++i) kk += sx[grp][i] * Wksum[i * DK + j16];
    sk[grp][j16] = kk;
    if (grp < nb) kb[(size_t)(n0 + grp) * DK + j16] = kk;
  }
  __syncthreads();
  int colD = lane & 15, quad = lane >> 4;
#pragma unroll
  for (int t = 0; t < 4; ++t) {  // 16 tasks: mat(2) x ct(8)
    int g = wvid * 4 + t;
    int mat = g >> 3, ct = g & 7;
    const unsigned short* P = mat ? vpack : qpack;
    f32x4v acc = {0.f, 0.f, 0.f, 0.f};
#pragma unroll
    for (int kt = 0; kt < 2; ++kt) {
      bf16x8 a = *(const bf16x8*)&afrag[kt][lane][0];
      bf16x8 b = *(const bf16x8*)(P + ((size_t)(ct * 2 + kt) * 64 + lane) * 8);
      acc = __builtin_amdgcn_mfma_f32_16x16x32_bf16(a, b, acc, 0, 0, 0);
    }
    unsigned short* out = mat ? vxh : qxh;
#pragma unroll
    for (int reg = 0; reg < 4; ++reg) {
      int node = quad * 4 + reg;
      if (node < nb) out[(size_t)(n0 + node) * HID + ct * 16 + colD] = f2bf(acc[reg]);
    }
  }
  if (d < HEAD * FEDGE) {  // M[n][h][16-padded]
    int hh = d / FEDGE, tt = d - hh * FEDGE;
    float crow[16];
    *(float4*)&crow[0] = *(const float4*)&C[tt * HID + hh * DK + 0];
    *(float4*)&crow[4] = *(const float4*)&C[tt * HID + hh * DK + 4];
    *(float4*)&crow[8] = *(const float4*)&C[tt * HID + hh * DK + 8];
    *(float4*)&crow[12] = *(const float4*)&C[tt * HID + hh * DK + 12];
    for (int r = 0; r < nb; ++r) {
      float m = 0.f;
#pragma unroll
      for (int j = 0; j < DK; ++j) m += sk[r][j] * crow[j];
      Mout[((size_t)(n0 + r) * HEAD + hh) * 16 + tt] = m;
    }
  }
}

// Fused post(layer l) -> k1(layer l+1) with MFMA GEMMs. qx/vx outputs bf16.
__global__ __launch_bounds__(256) void k_post_k1(
    const float* __restrict__ agg, const unsigned short* __restrict__ opack,
    const float* __restrict__ bo, const float* __restrict__ gg, const float* __restrict__ bb,
    const unsigned short* __restrict__ qpack, const unsigned short* __restrict__ vpack,
    const float* __restrict__ Wksum, const float* __restrict__ C,
    unsigned short* __restrict__ qxh, float* __restrict__ kb, unsigned short* __restrict__ vxh,
    float* __restrict__ Mout, int N) {
  int d = threadIdx.x;
  int n0 = blockIdx.x * 16;
  int nb = min(16, N - n0);
  __shared__ __align__(16) unsigned short afrag[4][64][8];
  __shared__ __align__(16) float sz[16][132];
  __shared__ __align__(16) unsigned short hfrag[4][64][8];
  __shared__ float sk[16][DK];
  int lane = d & 63, wvid = d >> 6;
  {  // stage 1: agg -> bf16 A-fragments (wave w owns K-chunk w)
    int kt = wvid;
    int m = lane & 15, k0 = kt * 32 + (lane >> 4) * 8;
    const float* p = agg + (size_t)(n0 + m) * HID + k0;
    float4 x0 = *(const float4*)p;
    float4 x1 = *(const float4*)(p + 4);
    store_bf8(&afrag[kt][lane][0], x0, x1);
  }
  __syncthreads();
  // stage 2: z = agg@Wo + bo via MFMA; wave w -> col-tiles 2w, 2w+1
  int colD = lane & 15, quad = lane >> 4;
  {
    int ct0 = wvid * 2, ct1 = wvid * 2 + 1;
    float bias0 = bo[ct0 * 16 + colD], bias1 = bo[ct1 * 16 + colD];
    f32x4v acc0 = {bias0, bias0, bias0, bias0};
    f32x4v acc1 = {bias1, bias1, bias1, bias1};
#pragma unroll
    for (int kt = 0; kt < 4; ++kt) {
      bf16x8 a = *(const bf16x8*)&afrag[kt][lane][0];
      bf16x8 b0 = *(const bf16x8*)(opack + ((size_t)(ct0 * 4 + kt) * 64 + lane) * 8);
      bf16x8 b1 = *(const bf16x8*)(opack + ((size_t)(ct1 * 4 + kt) * 64 + lane) * 8);
      acc0 = __builtin_amdgcn_mfma_f32_16x16x32_bf16(a, b0, acc0, 0, 0, 0);
      acc1 = __builtin_amdgcn_mfma_f32_16x16x32_bf16(a, b1, acc1, 0, 0, 0);
    }
#pragma unroll
    for (int reg = 0; reg < 4; ++reg) {
      int node = quad * 4 + reg;
      sz[node][ct0 * 16 + colD] = acc0[reg];
      sz[node][ct1 * 16 + colD] = acc1[reg];
    }
  }
  __syncthreads();
  // stage 3: LN x2 + tanh (shuffle-based), write h back to sz (fp32) + hfrag (bf16)
  {
    int c4 = d & 31, rs = d >> 5;
    int col0 = c4 * 4, r0 = rs * 2;
    float4 zA = *(const float4*)&sz[r0][col0];
    float4 zB = *(const float4*)&sz[r0 + 1][col0];
    float4 g4 = *(const float4*)&gg[col0];
    float4 b4 = *(const float4*)&bb[col0];
#pragma unroll
    for (int pass = 0; pass < 2; ++pass) {
      float sA = zA.x + zA.y + zA.z + zA.w;
      float qA = zA.x * zA.x + zA.y * zA.y + zA.z * zA.z + zA.w * zA.w;
      float sB = zB.x + zB.y + zB.z + zB.w;
      float qB = zB.x * zB.x + zB.y * zB.y + zB.z * zB.z + zB.w * zB.w;
#pragma unroll
      for (int o = 16; o; o >>= 1) {
        sA += __shfl_xor(sA, o, 32);
        qA += __shfl_xor(qA, o, 32);
        sB += __shfl_xor(sB, o, 32);
        qB += __shfl_xor(qB, o, 32);
      }
      float mA = sA * (1.f / 128.f);
      float iA = rsqrtf(fmaxf(qA * (1.f / 128.f) - mA * mA, 0.f) + 1e-5f);
      float mB = sB * (1.f / 128.f);
      float iB = rsqrtf(fmaxf(qB * (1.f / 128.f) - mB * mB, 0.f) + 1e-5f);
      zA.x = (zA.x - mA) * iA * g4.x + b4.x;
      zA.y = (zA.y - mA) * iA * g4.y + b4.y;
      zA.z = (zA.z - mA) * iA * g4.z + b4.z;
      zA.w = (zA.w - mA) * iA * g4.w + b4.w;
      zB.x = (zB.x - mB) * iB * g4.x + b4.x;
      zB.y = (zB.y - mB) * iB * g4.y + b4.y;
      zB.z = (zB.z - mB) * iB * g4.z + b4.z;
      zB.w = (zB.w - mB) * iB * g4.w + b4.w;
    }
    zA.x = tanhf(zA.x);
    zA.y = tanhf(zA.y);
    zA.z = tanhf(zA.z);
    zA.w = tanhf(zA.w);
    zB.x = tanhf(zB.x);
    zB.y = tanhf(zB.y);
    zB.z = tanhf(zB.z);
    zB.w = tanhf(zB.w);
    *(float4*)&sz[r0][col0] = zA;
    *(float4*)&sz[r0 + 1][col0] = zB;
    int chunk = col0 >> 5, qd = (col0 >> 3) & 3, eo = col0 & 7;
    unsigned int loA = (unsigned)f2bf(zA.x) | ((unsigned)f2bf(zA.y) << 16);
    unsigned int hiA = (unsigned)f2bf(zA.z) | ((unsigned)f2bf(zA.w) << 16);
    unsigned int loB = (unsigned)f2bf(zB.x) | ((unsigned)f2bf(zB.y) << 16);
    unsigned int hiB = (unsigned)f2bf(zB.z) | ((unsigned)f2bf(zB.w) << 16);
    unsigned short* pA = &hfrag[chunk][(r0 & 15) + qd * 16][eo];
    unsigned short* pB = &hfrag[chunk][((r0 + 1) & 15) + qd * 16][eo];
    *(unsigned int*)pA = loA;
    *(unsigned int*)(pA + 2) = hiA;
    *(unsigned int*)pB = loB;
    *(unsigned int*)(pB + 2) = hiB;
  }
  __syncthreads();
  // stage 4: q/v MFMA (16 tasks over 4 waves)
#pragma unroll
  for (int t = 0; t < 4; ++t) {
    int g = wvid * 4 + t;
    int mat = g >> 3, ct = g & 7;
    const unsigned short* P = mat ? vpack : qpack;
    f32x4v acc = {0.f, 0.f, 0.f, 0.f};
#pragma unroll
    for (int kt = 0; kt < 4; ++kt) {
      bf16x8 a = *(const bf16x8*)&hfrag[kt][lane][0];
      bf16x8 b = *(const bf16x8*)(P + ((size_t)(ct * 4 + kt) * 64 + lane) * 8);
      acc = __builtin_amdgcn_mfma_f32_16x16x32_bf16(a, b, acc, 0, 0, 0);
    }
    unsigned short* out = mat ? vxh : qxh;
#pragma unroll
    for (int reg = 0; reg < 4; ++reg) {
      int node = quad * 4 + reg;
      if (node < nb) out[(size_t)(n0 + node) * HID + ct * 16 + colD] = f2bf(acc[reg]);
    }
  }
  // stage 5: k = h @ Wksum (fp32, from sz)
  int grp = d >> 4, j16 = d & 15;
  {
    float kk = 0.f;
    for (int i = 0; i < HID; ++i) kk += sz[grp][i] * Wksum[i * DK + j16];
    sk[grp][j16] = kk;
    if (grp < nb) kb[(size_t)(n0 + grp) * DK + j16] = kk;
  }
  __syncthreads();
  if (d < HEAD * FEDGE) {
    int hh = d / FEDGE, tt = d - hh * FEDGE;
    float crow[16];
    *(float4*)&crow[0] = *(const float4*)&C[tt * HID + hh * DK + 0];
    *(float4*)&crow[4] = *(const float4*)&C[tt * HID + hh * DK + 4];
    *(float4*)&crow[8] = *(const float4*)&C[tt * HID + hh * DK + 8];
    *(float4*)&crow[12] = *(const float4*)&C[tt * HID + hh * DK + 12];
    for (int r = 0; r < nb; ++r) {
      float m = 0.f;
#pragma unroll
      for (int j = 0; j < DK; ++j) m += sk[r][j] * crow[j];
      Mout[((size_t)(n0 + r) * HEAD + hh) * 16 + tt] = m;
    }
  }
}

// Two nodes per 256-thread block (independent 128-thread halves). Energies
// (edge,head)-parallel from bf16 qx, chunked online softmax (chunk count unified
// across halves so barriers match), aggregation from bf16 vx.
__global__ __launch_bounds__(256) void k3_gather2(
    const int* __restrict__ off, const int* __restrict__ scsr_s, const float* __restrict__ sea,
    const unsigned short* __restrict__ qxh, const float* __restrict__ kb,
    const float* __restrict__ Mbuf, const unsigned short* __restrict__ vxh,
    const float* __restrict__ WeWv, float* __restrict__ agg, int count,
    const int* __restrict__ nodemap, int use_map) {
  int pb = blockIdx.x;
  int d = threadIdx.x;
  int half = d >> 7, d7 = d & 127;
  int P = (count + 1) >> 1;
  int p = ((P & 7) == 0) ? ((pb & 7) * (P >> 3) + (pb >> 3)) : pb;
  int idx = 2 * p + half;
  if (idx >= count) idx = count - 1;
  int n = use_map ? nodemap[idx] : idx;
  int oi = idx;
  int j16 = d7 & 15, hd = d7 >> 4;
  __shared__ float sen[2][CH * 8];
  __shared__ float ssea[2][CH * 10];
  __shared__ int ss[2][CH];
  __shared__ float sT[2][HEAD * FEDGE];
  __shared__ __align__(16) float skb[2][DK];
  __shared__ float sM[2][128];
  __shared__ int scnt[2];
  int base = off[n] + n;
  int cnt = off[n + 1] + n + 1 - base;  // deg + 1 (self first)
  if (d7 < DK) skb[half][d7] = kb[(size_t)n * DK + d7];
  sM[half][d7] = Mbuf[(size_t)n * 128 + d7];  // M[n][h][t] at h*16+t
  if (d7 == 0) scnt[half] = cnt;
  __syncthreads();
  int cmax = max(scnt[0], scnt[1]);
  bool doT = (j16 < FEDGE);
  float m = -1e30f, l = 0.f, accv = 0.f, T = 0.f;
  for (int c0 = 0; c0 < cmax; c0 += CH) {
    int cc = min(CH, cnt - c0);  // may be <= 0 for the shorter half
    for (int idx2 = d7; idx2 < cc * 10; idx2 += 128)
      ssea[half][idx2] = sea[(size_t)(base + c0) * 10 + idx2];
    if (d7 < cc) ss[half][d7] = scsr_s[base + c0 + d7];
    __syncthreads();
    // energies: thread d7 -> edge o=ob+(d7>>3), head h=d7&7; 16 edges per round
    for (int ob = 0; ob < cc; ob += 16) {
      int o = ob + (d7 >> 3);
      int h = d7 & 7;
      if (o < cc) {
        int s = ss[half][o];
        const uint4* qp = (const uint4*)(qxh + (size_t)s * HID + h * DK);
        uint4 qa = qp[0], qb = qp[1];
        const float* kbp = &skb[half][0];
        float en = bflo(qa.x) * kbp[0] + bfhi(qa.x) * kbp[1] + bflo(qa.y) * kbp[2] +
                   bfhi(qa.y) * kbp[3] + bflo(qa.z) * kbp[4] + bfhi(qa.z) * kbp[5] +
                   bflo(qa.w) * kbp[6] + bfhi(qa.w) * kbp[7] + bflo(qb.x) * kbp[8] +
                   bfhi(qb.x) * kbp[9] + bflo(qb.y) * kbp[10] + bfhi(qb.y) * kbp[11] +
                   bflo(qb.z) * kbp[12] + bfhi(qb.z) * kbp[13] + bflo(qb.w) * kbp[14] +
                   bfhi(qb.w) * kbp[15];
        if ((c0 + o) > 0) {
#pragma unroll
          for (int u = 0; u < FEDGE; ++u) en += sM[half][h * DK + u] * ssea[half][o * 10 + u];
        }
        sen[half][o * 8 + h] = en * ESCALE;
      }
    }
    __syncthreads();
    float mloc = -1e30f;
    for (int o = 0; o < cc; ++o) mloc = fmaxf(mloc, sen[half][o * 8 + hd]);
    float mnew = fmaxf(m, mloc);
    float alpha = __expf(m - mnew);
    l *= alpha;
    accv *= alpha;
    T *= alpha;
#pragma unroll 2
    for (int o = 0; o < cc; ++o) {
      int s = ss[half][o];
      float pp = __expf(sen[half][o * 8 + hd] - mnew);
      l += pp;
      float vv = __uint_as_float((unsigned)vxh[(size_t)s * HID + d7] << 16);
      accv += pp * vv;
      if (doT && (c0 + o) > 0) T += pp * ssea[half][o * 10 + j16];
    }
    m = mnew;
    __syncthreads();
  }
  float inv = 1.f / l;
  if (doT) sT[half][hd * FEDGE + j16] = T * inv;
  __syncthreads();
  float y = accv * inv;
#pragma unroll
  for (int t = 0; t < FEDGE; ++t) y += sT[half][hd * FEDGE + t] * WeWv[t * HID + d7];
  agg[(size_t)oi * HID + d7] = y;
}

// Final epilogue (compact rows): fp32 tile + shuffle LN + tanh, straight to hout.
__global__ __launch_bounds__(256) void k_post(const float* __restrict__ agg,
                                              const float* __restrict__ Wo,
                                              const float* __restrict__ bo,
                                              const float* __restrict__ gg,
                                              const float* __restrict__ bb,
                                              float* __restrict__ hout, int N) {
  int d = threadIdx.x;
  int n0 = blockIdx.x * 16;
  int nb = min(16, N - n0);
  __shared__ __align__(16) float sh[16][132];
  {
    int col = d & 127, h2 = d >> 7;
#pragma unroll
    for (int rr = 0; rr < 8; ++rr) {
      int r = h2 * 8 + rr;
      sh[r][col] = (r < nb) ? agg[(size_t)(n0 + r) * HID + col] : 0.f;
    }
  }
  __syncthreads();
  int c4 = d & 31, rs = d >> 5;
  int col0 = c4 * 4, r0 = rs * 2;
  float4 bv = *(const float4*)&bo[col0];
  float4 zA = bv, zB = bv;
  for (int k4 = 0; k4 < 32; ++k4) {
    float4 w0 = *(const float4*)&Wo[(k4 * 4 + 0) * HID + col0];
    float4 w1 = *(const float4*)&Wo[(k4 * 4 + 1) * HID + col0];
    float4 w2 = *(const float4*)&Wo[(k4 * 4 + 2) * HID + col0];
    float4 w3 = *(const float4*)&Wo[(k4 * 4 + 3) * HID + col0];
    float4 a0 = *(const float4*)&sh[r0][k4 * 4];
    float4 a1 = *(const float4*)&sh[r0 + 1][k4 * 4];
    fma4(zA, a0.x, w0);
    fma4(zA, a0.y, w1);
    fma4(zA, a0.z, w2);
    fma4(zA, a0.w, w3);
    fma4(zB, a1.x, w0);
    fma4(zB, a1.y, w1);
    fma4(zB, a1.z, w2);
    fma4(zB, a1.w, w3);
  }
  float4 g4 = *(const float4*)&gg[col0];
  float4 b4 = *(const float4*)&bb[col0];
#pragma unroll
  for (int pass = 0; pass < 2; ++pass) {
    float sA = zA.x + zA.y + zA.z + zA.w;
    float qA = zA.x * zA.x + zA.y * zA.y + zA.z * zA.z + zA.w * zA.w;
    float sB = zB.x + zB.y + zB.z + zB.w;
    float qB = zB.x * zB.x + zB.y * zB.y + zB.z * zB.z + zB.w * zB.w;
#pragma unroll
    for (int o = 16; o; o >>= 1) {
      sA += __shfl_xor(sA, o, 32);
      qA += __shfl_xor(qA, o, 32);
      sB += __shfl_xor(sB, o, 32);
      qB += __shfl_xor(qB, o, 32);
    }
    float mA = sA * (1.f / 128.f);
    float iA = rsqrtf(fmaxf(qA * (1.f / 128.f) - mA * mA, 0.f) + 1e-5f);
    float mB = sB * (1.f / 128.f);
    float iB = rsqrtf(fmaxf(qB * (1.f / 128.f) - mB * mB, 0.f) + 1e-5f);
    zA.x = (zA.x - mA) * iA * g4.x + b4.x;
    zA.y = (zA.y - mA) * iA * g4.y + b4.y;
    zA.z = (zA.z - mA) * iA * g4.z + b4.z;
    zA.w = (zA.w - mA) * iA * g4.w + b4.w;
    zB.x = (zB.x - mB) * iB * g4.x + b4.x;
    zB.y = (zB.y - mB) * iB * g4.y + b4.y;
    zB.z = (zB.z - mB) * iB * g4.z + b4.z;
    zB.w = (zB.w - mB) * iB * g4.w + b4.w;
  }
  if (r0 < nb) {
    float4 o0 = make_float4(tanhf(zA.x), tanhf(zA.y), tanhf(zA.z), tanhf(zA.w));
    *(float4*)&hout[(size_t)(n0 + r0) * HID + col0] = o0;
  }
  if (r0 + 1 < nb) {
    float4 o1 = make_float4(tanhf(zB.x), tanhf(zB.y), tanhf(zB.z), tanhf(zB.w));
    *(float4*)&hout[(size_t)(n0 + r0 + 1) * HID + col0] = o1;
  }
}

// Pool over compact interface rows: graph g reads rows g*per_g .. g*per_g+per_g-1.
__global__ __launch_bounds__(128) void k4_pool(const float* __restrict__ h,
                                               const float* __restrict__ gate,
                                               const float* __restrict__ W1,
                                               const float* __restrict__ b1,
                                               const float* __restrict__ W2,
                                               const float* __restrict__ b2,
                                               float* __restrict__ out, int per_g) {
  int g = blockIdx.x, d = threadIdx.x;
  __shared__ float satt[128], spool[HID], so[64], sv[2];
  size_t rbase = (size_t)g * per_g;
  float sc = -1e30f;
  if (d < per_g) {
    float s = 0.f;
    const float* hp = h + (rbase + d) * HID;
    for (int i = 0; i < HID; ++i) s += hp[i] * gate[i];
    sc = s;
  }
  satt[d] = sc;
  __syncthreads();
  if (d == 0) {
    float m = -1e30f;
    for (int i = 0; i < per_g; ++i) m = fmaxf(m, satt[i]);
    sv[0] = m;
  }
  __syncthreads();
  float m = sv[0];
  float ex = (d < per_g) ? __expf(sc - m) : 0.f;
  satt[d] = ex;
  __syncthreads();
  if (d == 0) {
    float su = 0.f;
    for (int i = 0; i < per_g; ++i) su += satt[i];
    sv[1] = 1.f / su;
  }
  __syncthreads();
  float inv = sv[1];
  float p = 0.f;
  for (int i = 0; i < per_g; ++i) p += satt[i] * h[(rbase + i) * HID + d];
  spool[d] = p * inv;
  __syncthreads();
  if (d < 64) {
    float o = b1[d];
    for (int i = 0; i < HID; ++i) o += spool[i] * W1[i * 64 + d];
    so[d] = tanhf(o);
  }
  __syncthreads();
  if (d == 0) {
    float z = b2[0];
    for (int i = 0; i < 64; ++i) z += so[i] * W2[i];
    out[g] = 1.f / (1.f + __expf(-z));
  }
}

extern "C" void kernel_launch(void* const* d_in, const int* in_sizes, int n_in, void* d_out,
                              int out_size, void* d_ws, size_t ws_size, hipStream_t stream) {
  const float* x = (const float*)d_in[0];
  const float* eattr = (const float*)d_in[1];
  const float* c0_We = (const float*)d_in[2];
  const float* c0_Wq = (const float*)d_in[3];
  const float* c0_Wk = (const float*)d_in[4];
  const float* c0_Wv = (const float*)d_in[5];
  const float* c0_Wo = (const float*)d_in[6];
  const float* c0_bo = (const float*)d_in[7];
  const float* c0_g = (const float*)d_in[8];
  const float* c0_b = (const float*)d_in[9];
  const float* cs_We = (const float*)d_in[10];
  const float* cs_Wq = (const float*)d_in[11];
  const float* cs_Wk = (const float*)d_in[12];
  const float* cs_Wv = (const float*)d_in[13];
  const float* cs_Wo = (const float*)d_in[14];
  const float* cs_bo = (const float*)d_in[15];
  const float* cs_g = (const float*)d_in[16];
  const float* cs_b = (const float*)d_in[17];
  const float* gate = (const float*)d_in[18];
  const float* W1 = (const float*)d_in[19];
  const float* b1 = (const float*)d_in[20];
  const float* W2 = (const float*)d_in[21];
  const float* b2 = (const float*)d_in[22];
  const int* ei = (const int*)d_in[23];
  const int* ipos = (const int*)d_in[25];

  int N = in_sizes[0] / FNODE;   // 20000
  int E = in_sizes[1] / FEDGE;   // 160000
  int G = out_size;              // 100
  int NI = in_sizes[25];         // 10000 interface nodes
  int per_g = NI / G;            // 100
  int ET = E + N;

  float* w = (float*)d_ws;
  float* hB = w;         w += (size_t)N * HID;
  float* aggb = w;       w += (size_t)N * HID;
  float* kb = w;         w += (size_t)N * DK;
  float* Mbuf = w;       w += (size_t)N * HEAD * 16;
  float* sea3 = w;       w += (size_t)3 * ET * FEDGE;
  float* C3 = w;         w += 3 * FEDGE * HID;
  float* WeWv3 = w;      w += 3 * FEDGE * HID;
  float* Gram3 = w;      w += 3 * FEDGE * FEDGE;
  float* Wksum3 = w;     w += 3 * HID * DK;
  unsigned short* qxh = (unsigned short*)w;  w += (size_t)N * HID / 2;
  unsigned short* vxh = (unsigned short*)w;  w += (size_t)N * HID / 2;
  unsigned short* qp3 = (unsigned short*)w;  w += 3 * 16384 / 2;
  unsigned short* vp3 = (unsigned short*)w;  w += 3 * 16384 / 2;
  unsigned short* op2 = (unsigned short*)w;  w += 2 * 16384 / 2;
  int* cnt = (int*)w;
  int* off = cnt + (N + 1);
  int* cur = off + (N + 1);
  int* scsr_s = cur + N;

  const float* Ws[3][8] = {
      {c0_We, c0_Wq, c0_Wk, c0_Wv, c0_Wo, c0_bo, c0_g, c0_b},
      {cs_We, cs_Wq, cs_Wk, cs_Wv, cs_Wo, cs_bo, cs_g, cs_b},
      {cs_We + FEDGE * HID, cs_Wq + HID * HID, cs_Wk + HID * HID, cs_Wv + HID * HID,
       cs_Wo + HID * HID, cs_bo + HID, cs_g + HID, cs_b + HID}};
  int fins[3] = {FNODE, HID, HID};

  PrepArgs prep;
  for (int l = 0; l < 3; ++l) {
    prep.We[l] = Ws[l][0];
    prep.Wq[l] = Ws[l][1];
    prep.Wk[l] = Ws[l][2];
    prep.Wv[l] = Ws[l][3];
    prep.C[l] = C3 + l * FEDGE * HID;
    prep.WeWv[l] = WeWv3 + l * FEDGE * HID;
    prep.Gram[l] = Gram3 + l * FEDGE * FEDGE;
    prep.Wksum[l] = Wksum3 + l * HID * DK;
    prep.fin[l] = fins[l];
  }
  PackArgs pa;
  int wpackN = 0;
  {
    const float* srcs[8] = {Ws[0][1], Ws[0][3], Ws[1][1], Ws[1][3],
                            Ws[2][1], Ws[2][3], Ws[0][4], Ws[1][4]};
    unsigned short* dsts[8] = {qp3, vp3, qp3 + 16384, vp3 + 16384, qp3 + 2 * 16384,
                               vp3 + 2 * 16384, op2, op2 + 16384};
    int fns[8] = {FNODE, FNODE, HID, HID, HID, HID, HID, HID};
    int kts[8] = {2, 2, 4, 4, 4, 4, 4, 4};
    for (int i = 0; i < 8; ++i) {
      pa.src[i] = srcs[i];
      pa.dst[i] = dsts[i];
      pa.fin[i] = fns[i];
      pa.kt[i] = kts[i];
      pa.blk_off[i] = wpackN;
      wpackN += 8 * kts[i];
    }
  }
  int wprepN = 3 * FEDGE;
  int zeroB = (N + 1 + 255) / 256;
  k_setup<<<wprepN + wpackN + zeroB, 256, 0, stream>>>(prep, pa, wprepN, wpackN, cnt, N + 1);

  k_count<<<(E + 255) / 256, 256, 0, stream>>>(ei, E, cnt);
  k_scan<<<1, 1024, 0, stream>>>(cnt, off, cur, scsr_s, N, E);
  k_fill_sea<<<(E + 255) / 256, 256, 0, stream>>>(ei, E, cur, scsr_s, eattr, Gram3, sea3, ET);

  k1_l2x<<<(N + 15) / 16, 256, 0, stream>>>(x, qp3, vp3, Wksum3, C3, qxh, kb, vxh, Mbuf, N);
  for (int l = 0; l < 3; ++l) {
    const float* sea_l = sea3 + (size_t)l * ET * FEDGE;
    if (l < 2) {
      k3_gather2<<<(N + 1) / 2, 256, 0, stream>>>(off, scsr_s, sea_l, qxh, kb, Mbuf, vxh,
                                                  WeWv3 + l * FEDGE * HID, aggb, N, ipos, 0);
      k_post_k1<<<(N + 15) / 16, 256, 0, stream>>>(
          aggb, op2 + l * 16384, Ws[l][5], Ws[l][6], Ws[l][7], qp3 + (l + 1) * 16384,
          vp3 + (l + 1) * 16384, Wksum3 + (l + 1) * HID * DK, C3 + (l + 1) * FEDGE * HID, qxh, kb,
          vxh, Mbuf, N);
    } else {
      // last layer: only interface nodes are consumed by pooling
      k3_gather2<<<(NI + 1) / 2, 256, 0, stream>>>(off, scsr_s, sea_l, qxh, kb, Mbuf, vxh,
                                                   WeWv3 + l * FEDGE * HID, aggb, NI, ipos, 1);
      k_post<<<(NI + 15) / 16, 256, 0, stream>>>(aggb, Ws[l][4], Ws[l][5], Ws[l][6], Ws[l][7], hB,
                                                 NI);
    }
  }
  k4_pool<<<G, 128, 0, stream>>>(hB, gate, W1, b1, W2, b2, (float*)d_out, per_g);
}

// Round 19
// 362.999 us; speedup vs baseline: 1.0965x; 1.0965x over previous
//
#include <hip/hip_runtime.h>
#include <math.h>

#define HID 128
#define HEAD 8
#define DK 16
#define FEDGE 10
#define FNODE 36
#define ESCALE 0.08838834764831845f  // 1/sqrt(128)
#define CH 32

typedef float f32x4v __attribute__((ext_vector_type(4)));
typedef short bf16x8 __attribute__((ext_vector_type(8)));

struct PackArgs {
  const float* src[8];
  unsigned short* dst[8];
  int fin[8];
  int kt[8];
  int blk_off[8];
};

struct PrepArgs {
  const float* We[3];
  const float* Wq[3];
  const float* Wk[3];
  const float* Wv[3];
  float* C[3];
  float* WeWv[3];
  float* Gram[3];
  float* Wksum[3];
  int fin[3];
};

__device__ __forceinline__ void fma4(float4& z, float s, const float4& w) {
  z.x += s * w.x;
  z.y += s * w.y;
  z.z += s * w.z;
  z.w += s * w.w;
}

__device__ __forceinline__ unsigned short f2bf(float f) {
  unsigned int u = __float_as_uint(f);
  u += 0x7fffu + ((u >> 16) & 1u);
  return (unsigned short)(u >> 16);
}

__device__ __forceinline__ float bflo(unsigned int u) { return __uint_as_float(u << 16); }
__device__ __forceinline__ float bfhi(unsigned int u) { return __uint_as_float(u & 0xffff0000u); }

__device__ __forceinline__ void store_bf8(unsigned short* p, float4 a, float4 b) {
  uint4 u;
  u.x = (unsigned)f2bf(a.x) | ((unsigned)f2bf(a.y) << 16);
  u.y = (unsigned)f2bf(a.z) | ((unsigned)f2bf(a.w) << 16);
  u.z = (unsigned)f2bf(b.x) | ((unsigned)f2bf(b.y) << 16);
  u.w = (unsigned)f2bf(b.z) | ((unsigned)f2bf(b.w) << 16);
  *(uint4*)p = u;
}

// Fused setup: [0, wprepN) weight precompute; [wprepN, wprepN+wpackN) bf16 pack;
// rest: zero cnt. All parts independent (pack reads original weights).
__global__ __launch_bounds__(256) void k_setup(PrepArgs a, PackArgs pa, int wprepN, int wpackN,
                                               int* __restrict__ cnt, int nzero) {
  int b = blockIdx.x, d = threadIdx.x;
  __shared__ float sw[HID];
  if (b < wprepN) {
    int l = b / FEDGE, t = b - l * FEDGE;
    int fin = a.fin[l];
    const float* We = a.We[l];
    if (d < fin) sw[d] = We[t * fin + d];
    __syncthreads();
    if (d < 128) {
      const float* Wq = a.Wq[l];
      const float* Wv = a.Wv[l];
      const float* Wk = a.Wk[l];
      float c = 0.f, wv = 0.f;
      for (int i = 0; i < fin; ++i) {
        c += sw[i] * Wq[i * HID + d];
        wv += sw[i] * Wv[i * HID + d];
      }
      a.C[l][t * HID + d] = c;
      a.WeWv[l][t * HID + d] = wv;
      if (d < FEDGE) {
        float g = 0.f;
        for (int i = 0; i < fin; ++i) g += sw[i] * We[d * fin + i];
        a.Gram[l][t * FEDGE + d] = g;
      }
      for (int r = t; r < fin; r += FEDGE) {
        if (d < DK) {
          float s = 0.f;
#pragma unroll
          for (int hh = 0; hh < HEAD; ++hh) s += Wk[r * HID + hh * DK + d];
          a.Wksum[l][r * DK + d] = s;
        }
      }
    }
    return;
  }
  if (b < wprepN + wpackN) {
    if (d >= 64) return;
    int bb = b - wprepN;
    int lane = d;
    int m = 0;
#pragma unroll
    for (int i = 1; i < 8; ++i) m += (bb >= pa.blk_off[i]);
    int local = bb - pa.blk_off[m];
    int KT = pa.kt[m];
    int ct = local / KT, kt = local - ct * KT;
    const float* W = pa.src[m];
    int fin = pa.fin[m];
    int col = ct * 16 + (lane & 15);
    int kbase = kt * 32 + (lane >> 4) * 8;
    float v[8];
#pragma unroll
    for (int j = 0; j < 8; ++j) {
      int k = kbase + j;
      v[j] = (k < fin) ? W[k * HID + col] : 0.f;
    }
    store_bf8(pa.dst[m] + (size_t)local * 512 + lane * 8, make_float4(v[0], v[1], v[2], v[3]),
              make_float4(v[4], v[5], v[6], v[7]));
    return;
  }
  int i = (b - wprepN - wpackN) * 256 + d;
  if (i < nzero) cnt[i] = 0;
}

__global__ void k_count(const int* __restrict__ ei, int E, int* __restrict__ cnt) {
  int e = blockIdx.x * 256 + threadIdx.x;
  if (e >= E) return;
  atomicAdd(&cnt[ei[E + e]], 1);
}

__global__ __launch_bounds__(1024) void k_scan(const int* __restrict__ cnt, int* __restrict__ off,
                                               int* __restrict__ cur, int* __restrict__ scsr_s,
                                               int n, int total) {
  __shared__ int s[1024];
  int t = threadIdx.x;
  const int C = (n + 1023) / 1024;
  int local[32];
  int base = t * C;
  int sum = 0;
  for (int j = 0; j < C; ++j) {
    int i = base + j;
    int v = (i < n) ? cnt[i] : 0;
    local[j] = sum;
    sum += v;
  }
  s[t] = sum;
  __syncthreads();
  for (int dd = 1; dd < 1024; dd <<= 1) {
    int v = (t >= dd) ? s[t - dd] : 0;
    __syncthreads();
    s[t] += v;
    __syncthreads();
  }
  int excl = (t == 0) ? 0 : s[t - 1];
  for (int j = 0; j < C; ++j) {
    int i = base + j;
    if (i < n) {
      int o = excl + local[j];
      off[i] = o;
      cur[i] = o;
      scsr_s[o + i] = i;  // self-loop slot source = the node itself
    }
  }
  if (t == 0) off[n] = total;
}

// CSR fill + per-layer sea in one pass: node n's slots = [off[n]+n, off[n+1]+n+1),
// slot off[n]+n is the self-loop; edge e lands at pos = cur++ + t + 1.
__global__ void k_fill_sea(const int* __restrict__ ei, int E, int* __restrict__ cur,
                           int* __restrict__ scsr_s, const float* __restrict__ eattr,
                           const float* __restrict__ Gram3, float* __restrict__ sea3, int ET) {
  int e = blockIdx.x * 256 + threadIdx.x;
  if (e >= E) return;
  int t = ei[E + e];
  int pos = atomicAdd(&cur[t], 1) + t + 1;
  scsr_s[pos] = ei[e];
  float a[FEDGE];
  float ss = 0.f;
  for (int i = 0; i < FEDGE; ++i) {
    a[i] = eattr[(size_t)e * FEDGE + i];
    ss += a[i] * a[i];
  }
  float s0 = 1.f / fmaxf(sqrtf(ss), 1e-12f);
  for (int i = 0; i < FEDGE; ++i) a[i] *= s0;
  for (int l = 0; l < 3; ++l) {
    const float* G = Gram3 + l * FEDGE * FEDGE;
    float gp = 0.f;
#pragma unroll
    for (int j = 0; j < FEDGE; ++j) {
      float tt = 0.f;
#pragma unroll
      for (int u = 0; u < FEDGE; ++u) tt += G[j * FEDGE + u] * a[u];
      gp += tt * a[j];
    }
    float scl = 1.f / fmaxf(sqrtf(gp), 1e-12f);
    float* sp = sea3 + (size_t)l * ET * FEDGE + (size_t)pos * FEDGE;
#pragma unroll
    for (int u = 0; u < FEDGE; ++u) sp[u] = scl * a[u];
  }
}

// Layer-0 k1: l2norm(x) -> MFMA q/v (bf16, K padded 36->64), k/M fp32.
__global__ __launch_bounds__(256) void k1_l2x(
    const float* __restrict__ x, const unsigned short* __restrict__ qpack,
    const unsigned short* __restrict__ vpack, const float* __restrict__ Wksum,
    const float* __restrict__ C, unsigned short* __restrict__ qxh, float* __restrict__ kb,
    unsigned short* __restrict__ vxh, float* __restrict__ Mout, int N) {
  const int fin = FNODE;
  int d = threadIdx.x;
  int n0 = blockIdx.x * 16;
  int nb = min(16, N - n0);
  __shared__ __align__(16) float sx[16][40];
  __shared__ __align__(16) unsigned short afrag[2][64][8];
  __shared__ float sk[16][DK];
  {
    int col = d & 127, h2 = d >> 7;
#pragma unroll
    for (int rr = 0; rr < 8; ++rr) {
      int r = h2 * 8 + rr;
      if (col < fin) sx[r][col] = (r < nb) ? x[(size_t)(n0 + r) * fin + col] : 0.f;
    }
  }
  __syncthreads();
  int grp = d >> 4, j16 = d & 15;
  {  // l2norm row grp in-place
    float ssq = 0.f;
    for (int i = j16; i < fin; i += 16) ssq += sx[grp][i] * sx[grp][i];
#pragma unroll
    for (int o = 8; o; o >>= 1) ssq += __shfl_xor(ssq, o, 16);
    float scl = 1.f / fmaxf(sqrtf(ssq), 1e-12f);
    for (int i = j16; i < fin; i += 16) sx[grp][i] *= scl;
  }
  __syncthreads();
  int lane = d & 63, wvid = d >> 6;
  if (d < 128) {  // A-fragments (2 K-chunks of 32, zero-padded past fin)
    int kt = d >> 6;  // 0..1
    int m = lane & 15, k0 = kt * 32 + (lane >> 4) * 8;
    float v[8];
#pragma unroll
    for (int j = 0; j < 8; ++j) {
      int k = k0 + j;
      v[j] = (k < fin) ? sx[m][k] : 0.f;
    }
    store_bf8(&afrag[kt][lane][0], make_float4(v[0], v[1], v[2], v[3]),
              make_float4(v[4], v[5], v[6], v[7]));
  }
  {  // k = h @ Wksum (fp32)
    float kk = 0.f;
    for (int i = 0; i < fin; ++i) kk += sx[grp][i] * Wksum[i * DK + j16];
    sk[grp][j16] = kk;
    if (grp < nb) kb[(size_t)(n0 + grp) * DK + j16] = kk;
  }
  __syncthreads();
  int colD = lane & 15, quad = lane >> 4;
#pragma unroll
  for (int t = 0; t < 4; ++t) {  // 16 tasks: mat(2) x ct(8)
    int g = wvid * 4 + t;
    int mat = g >> 3, ct = g & 7;
    const unsigned short* P = mat ? vpack : qpack;
    f32x4v acc = {0.f, 0.f, 0.f, 0.f};
#pragma unroll
    for (int kt = 0; kt < 2; ++kt) {
      bf16x8 a = *(const bf16x8*)&afrag[kt][lane][0];
      bf16x8 b = *(const bf16x8*)(P + ((size_t)(ct * 2 + kt) * 64 + lane) * 8);
      acc = __builtin_amdgcn_mfma_f32_16x16x32_bf16(a, b, acc, 0, 0, 0);
    }
    unsigned short* out = mat ? vxh : qxh;
#pragma unroll
    for (int reg = 0; reg < 4; ++reg) {
      int node = quad * 4 + reg;
      if (node < nb) out[(size_t)(n0 + node) * HID + ct * 16 + colD] = f2bf(acc[reg]);
    }
  }
  if (d < HEAD * FEDGE) {  // M[n][h][16-padded]
    int hh = d / FEDGE, tt = d - hh * FEDGE;
    float crow[16];
    *(float4*)&crow[0] = *(const float4*)&C[tt * HID + hh * DK + 0];
    *(float4*)&crow[4] = *(const float4*)&C[tt * HID + hh * DK + 4];
    *(float4*)&crow[8] = *(const float4*)&C[tt * HID + hh * DK + 8];
    *(float4*)&crow[12] = *(const float4*)&C[tt * HID + hh * DK + 12];
    for (int r = 0; r < nb; ++r) {
      float m = 0.f;
#pragma unroll
      for (int j = 0; j < DK; ++j) m += sk[r][j] * crow[j];
      Mout[((size_t)(n0 + r) * HEAD + hh) * 16 + tt] = m;
    }
  }
}

// Fused post(layer l) -> k1(layer l+1) with MFMA GEMMs. qx/vx outputs bf16.
__global__ __launch_bounds__(256) void k_post_k1(
    const float* __restrict__ agg, const unsigned short* __restrict__ opack,
    const float* __restrict__ bo, const float* __restrict__ gg, const float* __restrict__ bb,
    const unsigned short* __restrict__ qpack, const unsigned short* __restrict__ vpack,
    const float* __restrict__ Wksum, const float* __restrict__ C,
    unsigned short* __restrict__ qxh, float* __restrict__ kb, unsigned short* __restrict__ vxh,
    float* __restrict__ Mout, int N) {
  int d = threadIdx.x;
  int n0 = blockIdx.x * 16;
  int nb = min(16, N - n0);
  __shared__ __align__(16) unsigned short afrag[4][64][8];
  __shared__ __align__(16) float sz[16][132];
  __shared__ __align__(16) unsigned short hfrag[4][64][8];
  __shared__ float sk[16][DK];
  int lane = d & 63, wvid = d >> 6;
  {  // stage 1: agg -> bf16 A-fragments (wave w owns K-chunk w)
    int kt = wvid;
    int m = lane & 15, k0 = kt * 32 + (lane >> 4) * 8;
    const float* p = agg + (size_t)(n0 + m) * HID + k0;
    float4 x0 = *(const float4*)p;
    float4 x1 = *(const float4*)(p + 4);
    store_bf8(&afrag[kt][lane][0], x0, x1);
  }
  __syncthreads();
  // stage 2: z = agg@Wo + bo via MFMA; wave w -> col-tiles 2w, 2w+1
  int colD = lane & 15, quad = lane >> 4;
  {
    int ct0 = wvid * 2, ct1 = wvid * 2 + 1;
    float bias0 = bo[ct0 * 16 + colD], bias1 = bo[ct1 * 16 + colD];
    f32x4v acc0 = {bias0, bias0, bias0, bias0};
    f32x4v acc1 = {bias1, bias1, bias1, bias1};
#pragma unroll
    for (int kt = 0; kt < 4; ++kt) {
      bf16x8 a = *(const bf16x8*)&afrag[kt][lane][0];
      bf16x8 b0 = *(const bf16x8*)(opack + ((size_t)(ct0 * 4 + kt) * 64 + lane) * 8);
      bf16x8 b1 = *(const bf16x8*)(opack + ((size_t)(ct1 * 4 + kt) * 64 + lane) * 8);
      acc0 = __builtin_amdgcn_mfma_f32_16x16x32_bf16(a, b0, acc0, 0, 0, 0);
      acc1 = __builtin_amdgcn_mfma_f32_16x16x32_bf16(a, b1, acc1, 0, 0, 0);
    }
#pragma unroll
    for (int reg = 0; reg < 4; ++reg) {
      int node = quad * 4 + reg;
      sz[node][ct0 * 16 + colD] = acc0[reg];
      sz[node][ct1 * 16 + colD] = acc1[reg];
    }
  }
  __syncthreads();
  // stage 3: LN x2 + tanh (shuffle-based), write h back to sz (fp32) + hfrag (bf16)
  {
    int c4 = d & 31, rs = d >> 5;
    int col0 = c4 * 4, r0 = rs * 2;
    float4 zA = *(const float4*)&sz[r0][col0];
    float4 zB = *(const float4*)&sz[r0 + 1][col0];
    float4 g4 = *(const float4*)&gg[col0];
    float4 b4 = *(const float4*)&bb[col0];
#pragma unroll
    for (int pass = 0; pass < 2; ++pass) {
      float sA = zA.x + zA.y + zA.z + zA.w;
      float qA = zA.x * zA.x + zA.y * zA.y + zA.z * zA.z + zA.w * zA.w;
      float sB = zB.x + zB.y + zB.z + zB.w;
      float qB = zB.x * zB.x + zB.y * zB.y + zB.z * zB.z + zB.w * zB.w;
#pragma unroll
      for (int o = 16; o; o >>= 1) {
        sA += __shfl_xor(sA, o, 32);
        qA += __shfl_xor(qA, o, 32);
        sB += __shfl_xor(sB, o, 32);
        qB += __shfl_xor(qB, o, 32);
      }
      float mA = sA * (1.f / 128.f);
      float iA = rsqrtf(fmaxf(qA * (1.f / 128.f) - mA * mA, 0.f) + 1e-5f);
      float mB = sB * (1.f / 128.f);
      float iB = rsqrtf(fmaxf(qB * (1.f / 128.f) - mB * mB, 0.f) + 1e-5f);
      zA.x = (zA.x - mA) * iA * g4.x + b4.x;
      zA.y = (zA.y - mA) * iA * g4.y + b4.y;
      zA.z = (zA.z - mA) * iA * g4.z + b4.z;
      zA.w = (zA.w - mA) * iA * g4.w + b4.w;
      zB.x = (zB.x - mB) * iB * g4.x + b4.x;
      zB.y = (zB.y - mB) * iB * g4.y + b4.y;
      zB.z = (zB.z - mB) * iB * g4.z + b4.z;
      zB.w = (zB.w - mB) * iB * g4.w + b4.w;
    }
    zA.x = tanhf(zA.x);
    zA.y = tanhf(zA.y);
    zA.z = tanhf(zA.z);
    zA.w = tanhf(zA.w);
    zB.x = tanhf(zB.x);
    zB.y = tanhf(zB.y);
    zB.z = tanhf(zB.z);
    zB.w = tanhf(zB.w);
    *(float4*)&sz[r0][col0] = zA;
    *(float4*)&sz[r0 + 1][col0] = zB;
    int chunk = col0 >> 5, qd = (col0 >> 3) & 3, eo = col0 & 7;
    unsigned int loA = (unsigned)f2bf(zA.x) | ((unsigned)f2bf(zA.y) << 16);
    unsigned int hiA = (unsigned)f2bf(zA.z) | ((unsigned)f2bf(zA.w) << 16);
    unsigned int loB = (unsigned)f2bf(zB.x) | ((unsigned)f2bf(zB.y) << 16);
    unsigned int hiB = (unsigned)f2bf(zB.z) | ((unsigned)f2bf(zB.w) << 16);
    unsigned short* pA = &hfrag[chunk][(r0 & 15) + qd * 16][eo];
    unsigned short* pB = &hfrag[chunk][((r0 + 1) & 15) + qd * 16][eo];
    *(unsigned int*)pA = loA;
    *(unsigned int*)(pA + 2) = hiA;
    *(unsigned int*)pB = loB;
    *(unsigned int*)(pB + 2) = hiB;
  }
  __syncthreads();
  // stage 4: q/v MFMA (16 tasks over 4 waves)
#pragma unroll
  for (int t = 0; t < 4; ++t) {
    int g = wvid * 4 + t;
    int mat = g >> 3, ct = g & 7;
    const unsigned short* P = mat ? vpack : qpack;
    f32x4v acc = {0.f, 0.f, 0.f, 0.f};
#pragma unroll
    for (int kt = 0; kt < 4; ++kt) {
      bf16x8 a = *(const bf16x8*)&hfrag[kt][lane][0];
      bf16x8 b = *(const bf16x8*)(P + ((size_t)(ct * 4 + kt) * 64 + lane) * 8);
      acc = __builtin_amdgcn_mfma_f32_16x16x32_bf16(a, b, acc, 0, 0, 0);
    }
    unsigned short* out = mat ? vxh : qxh;
#pragma unroll
    for (int reg = 0; reg < 4; ++reg) {
      int node = quad * 4 + reg;
      if (node < nb) out[(size_t)(n0 + node) * HID + ct * 16 + colD] = f2bf(acc[reg]);
    }
  }
  // stage 5: k = h @ Wksum (fp32, from sz)
  int grp = d >> 4, j16 = d & 15;
  {
    float kk = 0.f;
    for (int i = 0; i < HID; ++i) kk += sz[grp][i] * Wksum[i * DK + j16];
    sk[grp][j16] = kk;
    if (grp < nb) kb[(size_t)(n0 + grp) * DK + j16] = kk;
  }
  __syncthreads();
  if (d < HEAD * FEDGE) {
    int hh = d / FEDGE, tt = d - hh * FEDGE;
    float crow[16];
    *(float4*)&crow[0] = *(const float4*)&C[tt * HID + hh * DK + 0];
    *(float4*)&crow[4] = *(const float4*)&C[tt * HID + hh * DK + 4];
    *(float4*)&crow[8] = *(const float4*)&C[tt * HID + hh * DK + 8];
    *(float4*)&crow[12] = *(const float4*)&C[tt * HID + hh * DK + 12];
    for (int r = 0; r < nb; ++r) {
      float m = 0.f;
#pragma unroll
      for (int j = 0; j < DK; ++j) m += sk[r][j] * crow[j];
      Mout[((size_t)(n0 + r) * HEAD + hh) * 16 + tt] = m;
    }
  }
}

// Per-dst-node (128 threads, 1 node/block): energies (edge,head)-parallel from bf16
// qx, chunked online softmax, aggregation from bf16 vx. Optional nodemap for the
// interface-only last layer (compact output row b).
__global__ __launch_bounds__(128) void k3_gather(
    const int* __restrict__ off, const int* __restrict__ scsr_s, const float* __restrict__ sea,
    const unsigned short* __restrict__ qxh, const float* __restrict__ kb,
    const float* __restrict__ Mbuf, const unsigned short* __restrict__ vxh,
    const float* __restrict__ WeWv, float* __restrict__ agg, int N,
    const int* __restrict__ nodemap, int use_map) {
  int b = blockIdx.x;
  int n, oi;
  if (use_map) {
    n = nodemap[b];
    oi = b;
  } else {
    n = ((N & 7) == 0) ? ((b & 7) * (N >> 3) + (b >> 3)) : b;
    oi = n;
  }
  int d = threadIdx.x;
  int j16 = d & 15, hd = d >> 4;
  __shared__ float sen[CH * 8];
  __shared__ float ssea[CH * 10];
  __shared__ int ss[CH];
  __shared__ float sT[HEAD * FEDGE];
  __shared__ __align__(16) float skb[DK];
  __shared__ float sM[128];
  int base = off[n] + n;
  int cnt = off[n + 1] + n + 1 - base;  // deg + 1 (self first)
  if (d < DK) skb[d] = kb[(size_t)n * DK + d];
  sM[d] = Mbuf[(size_t)n * 128 + d];  // M[n][h][t] at h*16+t
  bool doT = (j16 < FEDGE);
  float m = -1e30f, l = 0.f, accv = 0.f, T = 0.f;
  for (int c0 = 0; c0 < cnt; c0 += CH) {
    int cc = min(CH, cnt - c0);
    for (int idx = d; idx < cc * 10; idx += 128)
      ssea[idx] = sea[(size_t)(base + c0) * 10 + idx];
    if (d < cc) ss[d] = scsr_s[base + c0 + d];
    __syncthreads();
    // energies: thread d -> edge o=ob+(d>>3), head h=d&7; 16 edges per round
    for (int ob = 0; ob < cc; ob += 16) {
      int o = ob + (d >> 3);
      int h = d & 7;
      if (o < cc) {
        int s = ss[o];
        const uint4* qp = (const uint4*)(qxh + (size_t)s * HID + h * DK);
        uint4 qa = qp[0], qb = qp[1];
        float en = bflo(qa.x) * skb[0] + bfhi(qa.x) * skb[1] + bflo(qa.y) * skb[2] +
                   bfhi(qa.y) * skb[3] + bflo(qa.z) * skb[4] + bfhi(qa.z) * skb[5] +
                   bflo(qa.w) * skb[6] + bfhi(qa.w) * skb[7] + bflo(qb.x) * skb[8] +
                   bfhi(qb.x) * skb[9] + bflo(qb.y) * skb[10] + bfhi(qb.y) * skb[11] +
                   bflo(qb.z) * skb[12] + bfhi(qb.z) * skb[13] + bflo(qb.w) * skb[14] +
                   bfhi(qb.w) * skb[15];
        if ((c0 + o) > 0) {
#pragma unroll
          for (int u = 0; u < FEDGE; ++u) en += sM[h * DK + u] * ssea[o * 10 + u];
        }
        sen[o * 8 + h] = en * ESCALE;
      }
    }
    __syncthreads();
    float mloc = -1e30f;
    for (int o = 0; o < cc; ++o) mloc = fmaxf(mloc, sen[o * 8 + hd]);
    float mnew = fmaxf(m, mloc);
    float alpha = __expf(m - mnew);
    l *= alpha;
    accv *= alpha;
    T *= alpha;
#pragma unroll 2
    for (int o = 0; o < cc; ++o) {
      int s = ss[o];
      float p = __expf(sen[o * 8 + hd] - mnew);
      l += p;
      float vv = __uint_as_float((unsigned)vxh[(size_t)s * HID + d] << 16);
      accv += p * vv;
      if (doT && (c0 + o) > 0) T += p * ssea[o * 10 + j16];
    }
    m = mnew;
    __syncthreads();
  }
  float inv = 1.f / l;
  if (doT) sT[hd * FEDGE + j16] = T * inv;
  __syncthreads();
  float y = accv * inv;
#pragma unroll
  for (int t = 0; t < FEDGE; ++t) y += sT[hd * FEDGE + t] * WeWv[t * HID + d];
  agg[(size_t)oi * HID + d] = y;
}

// Final epilogue (compact rows): fp32 tile + shuffle LN + tanh, straight to hout.
__global__ __launch_bounds__(256) void k_post(const float* __restrict__ agg,
                                              const float* __restrict__ Wo,
                                              const float* __restrict__ bo,
                                              const float* __restrict__ gg,
                                              const float* __restrict__ bb,
                                              float* __restrict__ hout, int N) {
  int d = threadIdx.x;
  int n0 = blockIdx.x * 16;
  int nb = min(16, N - n0);
  __shared__ __align__(16) float sh[16][132];
  {
    int col = d & 127, h2 = d >> 7;
#pragma unroll
    for (int rr = 0; rr < 8; ++rr) {
      int r = h2 * 8 + rr;
      sh[r][col] = (r < nb) ? agg[(size_t)(n0 + r) * HID + col] : 0.f;
    }
  }
  __syncthreads();
  int c4 = d & 31, rs = d >> 5;
  int col0 = c4 * 4, r0 = rs * 2;
  float4 bv = *(const float4*)&bo[col0];
  float4 zA = bv, zB = bv;
  for (int k4 = 0; k4 < 32; ++k4) {
    float4 w0 = *(const float4*)&Wo[(k4 * 4 + 0) * HID + col0];
    float4 w1 = *(const float4*)&Wo[(k4 * 4 + 1) * HID + col0];
    float4 w2 = *(const float4*)&Wo[(k4 * 4 + 2) * HID + col0];
    float4 w3 = *(const float4*)&Wo[(k4 * 4 + 3) * HID + col0];
    float4 a0 = *(const float4*)&sh[r0][k4 * 4];
    float4 a1 = *(const float4*)&sh[r0 + 1][k4 * 4];
    fma4(zA, a0.x, w0);
    fma4(zA, a0.y, w1);
    fma4(zA, a0.z, w2);
    fma4(zA, a0.w, w3);
    fma4(zB, a1.x, w0);
    fma4(zB, a1.y, w1);
    fma4(zB, a1.z, w2);
    fma4(zB, a1.w, w3);
  }
  float4 g4 = *(const float4*)&gg[col0];
  float4 b4 = *(const float4*)&bb[col0];
#pragma unroll
  for (int pass = 0; pass < 2; ++pass) {
    float sA = zA.x + zA.y + zA.z + zA.w;
    float qA = zA.x * zA.x + zA.y * zA.y + zA.z * zA.z + zA.w * zA.w;
    float sB = zB.x + zB.y + zB.z + zB.w;
    float qB = zB.x * zB.x + zB.y * zB.y + zB.z * zB.z + zB.w * zB.w;
#pragma unroll
    for (int o = 16; o; o >>= 1) {
      sA += __shfl_xor(sA, o, 32);
      qA += __shfl_xor(qA, o, 32);
      sB += __shfl_xor(sB, o, 32);
      qB += __shfl_xor(qB, o, 32);
    }
    float mA = sA * (1.f / 128.f);
    float iA = rsqrtf(fmaxf(qA * (1.f / 128.f) - mA * mA, 0.f) + 1e-5f);
    float mB = sB * (1.f / 128.f);
    float iB = rsqrtf(fmaxf(qB * (1.f / 128.f) - mB * mB, 0.f) + 1e-5f);
    zA.x = (zA.x - mA) * iA * g4.x + b4.x;
    zA.y = (zA.y - mA) * iA * g4.y + b4.y;
    zA.z = (zA.z - mA) * iA * g4.z + b4.z;
    zA.w = (zA.w - mA) * iA * g4.w + b4.w;
    zB.x = (zB.x - mB) * iB * g4.x + b4.x;
    zB.y = (zB.y - mB) * iB * g4.y + b4.y;
    zB.z = (zB.z - mB) * iB * g4.z + b4.z;
    zB.w = (zB.w - mB) * iB * g4.w + b4.w;
  }
  if (r0 < nb) {
    float4 o0 = make_float4(tanhf(zA.x), tanhf(zA.y), tanhf(zA.z), tanhf(zA.w));
    *(float4*)&hout[(size_t)(n0 + r0) * HID + col0] = o0;
  }
  if (r0 + 1 < nb) {
    float4 o1 = make_float4(tanhf(zB.x), tanhf(zB.y), tanhf(zB.z), tanhf(zB.w));
    *(float4*)&hout[(size_t)(n0 + r0 + 1) * HID + col0] = o1;
  }
}

// Pool over compact interface rows: graph g reads rows g*per_g .. g*per_g+per_g-1.
__global__ __launch_bounds__(128) void k4_pool(const float* __restrict__ h,
                                               const float* __restrict__ gate,
                                               const float* __restrict__ W1,
                                               const float* __restrict__ b1,
                                               const float* __restrict__ W2,
                                               const float* __restrict__ b2,
                                               float* __restrict__ out, int per_g) {
  int g = blockIdx.x, d = threadIdx.x;
  __shared__ float satt[128], spool[HID], so[64], sv[2];
  size_t rbase = (size_t)g * per_g;
  float sc = -1e30f;
  if (d < per_g) {
    float s = 0.f;
    const float* hp = h + (rbase + d) * HID;
    for (int i = 0; i < HID; ++i) s += hp[i] * gate[i];
    sc = s;
  }
  satt[d] = sc;
  __syncthreads();
  if (d == 0) {
    float m = -1e30f;
    for (int i = 0; i < per_g; ++i) m = fmaxf(m, satt[i]);
    sv[0] = m;
  }
  __syncthreads();
  float m = sv[0];
  float ex = (d < per_g) ? __expf(sc - m) : 0.f;
  satt[d] = ex;
  __syncthreads();
  if (d == 0) {
    float su = 0.f;
    for (int i = 0; i < per_g; ++i) su += satt[i];
    sv[1] = 1.f / su;
  }
  __syncthreads();
  float inv = sv[1];
  float p = 0.f;
  for (int i = 0; i < per_g; ++i) p += satt[i] * h[(rbase + i) * HID + d];
  spool[d] = p * inv;
  __syncthreads();
  if (d < 64) {
    float o = b1[d];
    for (int i = 0; i < HID; ++i) o += spool[i] * W1[i * 64 + d];
    so[d] = tanhf(o);
  }
  __syncthreads();
  if (d == 0) {
    float z = b2[0];
    for (int i = 0; i < 64; ++i) z += so[i] * W2[i];
    out[g] = 1.f / (1.f + __expf(-z));
  }
}

extern "C" void kernel_launch(void* const* d_in, const int* in_sizes, int n_in, void* d_out,
                              int out_size, void* d_ws, size_t ws_size, hipStream_t stream) {
  const float* x = (const float*)d_in[0];
  const float* eattr = (const float*)d_in[1];
  const float* c0_We = (const float*)d_in[2];
  const float* c0_Wq = (const float*)d_in[3];
  const float* c0_Wk = (const float*)d_in[4];
  const float* c0_Wv = (const float*)d_in[5];
  const float* c0_Wo = (const float*)d_in[6];
  const float* c0_bo = (const float*)d_in[7];
  const float* c0_g = (const float*)d_in[8];
  const float* c0_b = (const float*)d_in[9];
  const float* cs_We = (const float*)d_in[10];
  const float* cs_Wq = (const float*)d_in[11];
  const float* cs_Wk = (const float*)d_in[12];
  const float* cs_Wv = (const float*)d_in[13];
  const float* cs_Wo = (const float*)d_in[14];
  const float* cs_bo = (const float*)d_in[15];
  const float* cs_g = (const float*)d_in[16];
  const float* cs_b = (const float*)d_in[17];
  const float* gate = (const float*)d_in[18];
  const float* W1 = (const float*)d_in[19];
  const float* b1 = (const float*)d_in[20];
  const float* W2 = (const float*)d_in[21];
  const float* b2 = (const float*)d_in[22];
  const int* ei = (const int*)d_in[23];
  const int* ipos = (const int*)d_in[25];

  int N = in_sizes[0] / FNODE;   // 20000
  int E = in_sizes[1] / FEDGE;   // 160000
  int G = out_size;              // 100
  int NI = in_sizes[25];         // 10000 interface nodes
  int per_g = NI / G;            // 100
  int ET = E + N;

  float* w = (float*)d_ws;
  float* hB = w;         w += (size_t)N * HID;
  float* aggb = w;       w += (size_t)N * HID;
  float* kb = w;         w += (size_t)N * DK;
  float* Mbuf = w;       w += (size_t)N * HEAD * 16;
  float* sea3 = w;       w += (size_t)3 * ET * FEDGE;
  float* C3 = w;         w += 3 * FEDGE * HID;
  float* WeWv3 = w;      w += 3 * FEDGE * HID;
  float* Gram3 = w;      w += 3 * FEDGE * FEDGE;
  float* Wksum3 = w;     w += 3 * HID * DK;
  unsigned short* qxh = (unsigned short*)w;  w += (size_t)N * HID / 2;
  unsigned short* vxh = (unsigned short*)w;  w += (size_t)N * HID / 2;
  unsigned short* qp3 = (unsigned short*)w;  w += 3 * 16384 / 2;
  unsigned short* vp3 = (unsigned short*)w;  w += 3 * 16384 / 2;
  unsigned short* op2 = (unsigned short*)w;  w += 2 * 16384 / 2;
  int* cnt = (int*)w;
  int* off = cnt + (N + 1);
  int* cur = off + (N + 1);
  int* scsr_s = cur + N;

  const float* Ws[3][8] = {
      {c0_We, c0_Wq, c0_Wk, c0_Wv, c0_Wo, c0_bo, c0_g, c0_b},
      {cs_We, cs_Wq, cs_Wk, cs_Wv, cs_Wo, cs_bo, cs_g, cs_b},
      {cs_We + FEDGE * HID, cs_Wq + HID * HID, cs_Wk + HID * HID, cs_Wv + HID * HID,
       cs_Wo + HID * HID, cs_bo + HID, cs_g + HID, cs_b + HID}};
  int fins[3] = {FNODE, HID, HID};

  PrepArgs prep;
  for (int l = 0; l < 3; ++l) {
    prep.We[l] = Ws[l][0];
    prep.Wq[l] = Ws[l][1];
    prep.Wk[l] = Ws[l][2];
    prep.Wv[l] = Ws[l][3];
    prep.C[l] = C3 + l * FEDGE * HID;
    prep.WeWv[l] = WeWv3 + l * FEDGE * HID;
    prep.Gram[l] = Gram3 + l * FEDGE * FEDGE;
    prep.Wksum[l] = Wksum3 + l * HID * DK;
    prep.fin[l] = fins[l];
  }
  PackArgs pa;
  int wpackN = 0;
  {
    const float* srcs[8] = {Ws[0][1], Ws[0][3], Ws[1][1], Ws[1][3],
                            Ws[2][1], Ws[2][3], Ws[0][4], Ws[1][4]};
    unsigned short* dsts[8] = {qp3, vp3, qp3 + 16384, vp3 + 16384, qp3 + 2 * 16384,
                               vp3 + 2 * 16384, op2, op2 + 16384};
    int fns[8] = {FNODE, FNODE, HID, HID, HID, HID, HID, HID};
    int kts[8] = {2, 2, 4, 4, 4, 4, 4, 4};
    for (int i = 0; i < 8; ++i) {
      pa.src[i] = srcs[i];
      pa.dst[i] = dsts[i];
      pa.fin[i] = fns[i];
      pa.kt[i] = kts[i];
      pa.blk_off[i] = wpackN;
      wpackN += 8 * kts[i];
    }
  }
  int wprepN = 3 * FEDGE;
  int zeroB = (N + 1 + 255) / 256;
  k_setup<<<wprepN + wpackN + zeroB, 256, 0, stream>>>(prep, pa, wprepN, wpackN, cnt, N + 1);

  k_count<<<(E + 255) / 256, 256, 0, stream>>>(ei, E, cnt);
  k_scan<<<1, 1024, 0, stream>>>(cnt, off, cur, scsr_s, N, E);
  k_fill_sea<<<(E + 255) / 256, 256, 0, stream>>>(ei, E, cur, scsr_s, eattr, Gram3, sea3, ET);

  k1_l2x<<<(N + 15) / 16, 256, 0, stream>>>(x, qp3, vp3, Wksum3, C3, qxh, kb, vxh, Mbuf, N);
  for (int l = 0; l < 3; ++l) {
    const float* sea_l = sea3 + (size_t)l * ET * FEDGE;
    if (l < 2) {
      k3_gather<<<N, 128, 0, stream>>>(off, scsr_s, sea_l, qxh, kb, Mbuf, vxh,
                                       WeWv3 + l * FEDGE * HID, aggb, N, ipos, 0);
      k_post_k1<<<(N + 15) / 16, 256, 0, stream>>>(
          aggb, op2 + l * 16384, Ws[l][5], Ws[l][6], Ws[l][7], qp3 + (l + 1) * 16384,
          vp3 + (l + 1) * 16384, Wksum3 + (l + 1) * HID * DK, C3 + (l + 1) * FEDGE * HID, qxh, kb,
          vxh, Mbuf, N);
    } else {
      // last layer: only interface nodes are consumed by pooling
      k3_gather<<<NI, 128, 0, stream>>>(off, scsr_s, sea_l, qxh, kb, Mbuf, vxh,
                                        WeWv3 + l * FEDGE * HID, aggb, NI, ipos, 1);
      k_post<<<(NI + 15) / 16, 256, 0, stream>>>(aggb, Ws[l][4], Ws[l][5], Ws[l][6], Ws[l][7], hB,
                                                 NI);
    }
  }
  k4_pool<<<G, 128, 0, stream>>>(hB, gate, W1, b1, W2, b2, (float*)d_out, per_g);
}